// Round 5
// baseline (162.859 us; speedup 1.0000x reference)
//
#include <hip/hip_runtime.h>
#include <stdint.h>
#include <stddef.h>

// ---------------- problem constants ----------------
// B=2048, F0=39, D=16, layers 128/128/128, xk halves to 64 after each layer.
// R16: R15 + register-budget fix. R15 (G-GEMM: G_h[k,d]=bf16(x0*xk) folded
// into MFMA K-dim, 78 MFMAs/layer into persistent accs) ran at 100us with
// VGPR_Count=60: the compiler targeted 2 blocks/CU (LDS 62KB<80KB) -> cap 64,
// leaving ZERO regs for Wc/Wn/G -> W loads at point-of-use (vmcnt stall in
// every MFMA feed, wall 2050cyc/SIMD-h vs 620 matrix floor) + remat'd 64-bit
// address math (VALU 865 cyc/SIMD-h, SGPR 48->32). Fix: __launch_bounds__
// (1024,2) => cap 128 (empirical: arg2=8->32, arg2=4->64; also the HW cap for
// a 16-wave block) + W loads as uniform-SGPR base (wt + ihn*WBLK) + loop-
// invariant per-lane offset with imm offsets -> 1 SALU/h of address work.
// Grid 256, 1 block/CU (R12/R13: 2 desynced blocks/CU thrash W L1/L2).
#define F0N  39
#define SN   128
#define NB   8             // batches per block
#define X0TS 45            // f32 stride of X0T row (b,d): odd => conflict-free xs reads
#define KS   76            // f32 stride of XKF row (b,d): 16B-aligned rows
#define WBLK 8192          // u16 per (L,h) W block: 8 s-tiles x 2 chunks x 512
#define NHB2 234           // 3*39*2 prepass blocks (one per (L,h,k-half))

typedef __attribute__((ext_vector_type(8))) short short8;     // MFMA A/B operand
typedef __attribute__((ext_vector_type(4))) float floatx4;    // MFMA accumulator
typedef __attribute__((ext_vector_type(4))) uint32_t uint32x4;

__device__ __forceinline__ uint16_t f2bf(float f) {           // RNE f32->bf16
  uint32_t u = __float_as_uint(f);
  u += 0x7fffu + ((u >> 16) & 1u);
  return (uint16_t)(u >> 16);
}

// packed RNE f32x2 -> bf16x2 (single VALU op, gfx950)
__device__ __forceinline__ uint32_t cvtpk(float lo, float hi) {
  uint32_t r;
  asm("v_cvt_pk_bf16_f32 %0, %1, %2" : "=v"(r) : "v"(lo), "v"(hi));
  return r;
}

// ---------------- pre-pass: W fp32 -> bf16 A-fragment blocks ----------------
// One block per (L,h,ch). Output layout identical to R6-R15 (verified):
//   wt[(L*39+h)*WBLK + (st*2+ch)*512 + lane*8 + j],
//   value = W[h][k=ch*32+quad*8+j][s=st*16+l16].
__global__ __launch_bounds__(256) void cin_prepass(
    const float* __restrict__ w0, const float* __restrict__ w1,
    const float* __restrict__ w2, uint16_t* __restrict__ wt) {
  __shared__ float T[32 * 132];               // [k_local][s], +4 pad floats/row
  const int bc = blockIdx.x;                  // 0..233
  const int ch = bc & 1;
  const int lh = bc >> 1;                     // 0..116
  const int L = lh / F0N;
  const int h = lh - L * F0N;
  const float* W = (L == 0) ? w0 : ((L == 1) ? w1 : w2);
  const int fk = (L == 0) ? 39 : 64;
  const int tid = threadIdx.x;

  for (int e = tid; e < 4096; e += 256) {     // coalesced fp32 read
    int kc = e >> 7, s = e & 127;
    int k = ch * 32 + kc;
    T[kc * 132 + s] = (k < fk) ? W[(h * fk + k) * SN + s] : 0.0f;
  }
  __syncthreads();
  uint32_t* dst = (uint32_t*)(wt + (size_t)lh * WBLK);
  for (int i = tid; i < 2048; i += 256) {     // coalesced u32 writes, frag order
    int st = i >> 8, w = i & 255;
    int ln = w >> 2, jp = w & 3;
    int quad = ln >> 4, l16 = ln & 15;
    int k0 = quad * 8 + jp * 2;               // local k within this half
    int s = st * 16 + l16;
    dst[(size_t)(st * 2 + ch) * 256 + w] =
        (uint32_t)f2bf(T[k0 * 132 + s]) | ((uint32_t)f2bf(T[(k0 + 1) * 132 + s]) << 16);
  }
}

// ---------------- fused main kernel ----------------
// 256 blocks x 1024 threads (16 waves), 1 block/CU, 4 waves/SIMD.
// Wave (stg, bg): s-tiles st = stg*2+{0,1}, batches b = bg*2+{0,1}.
// Per layer: xk reg-cache (8 x floatx4); barrier; h-loop (39 iters): dist-1
// W prefetch (4 x dwordx4 from SGPR base + invariant lane offset), dist-1 xs
// prefetch (2 ds_read_b32), G build (16 pk-mul + 16 cvt_pk), 8 MFMA into 4
// persistent accs; epilogue: bias+relu, in-place XKF handoff (s<64),
// shfl-reduce over d=l16, out write.
__global__ __launch_bounds__(1024, 2) void cin_main(
    const float* __restrict__ x,       // (2048, 39, 16) fp32
    const float* __restrict__ bias0, const float* __restrict__ bias1,
    const float* __restrict__ bias2,
    const uint16_t* __restrict__ wt,   // A-frag bf16 weights (d_ws)
    float* __restrict__ out) {         // (2048, 256) fp32

  __shared__ __align__(16) float X0T[NB * 16 * X0TS];  // x0[b][d][h] f32, 23040 B
  __shared__ __align__(16) float XKF[NB * 16 * KS];    // xk[b][d][k] f32,  38912 B

  const int tid  = threadIdx.x;
  const int lane = tid & 63;
  const int wave = tid >> 6;           // 0..15
  const int stg  = wave >> 2;          // s-tile group 0..3 (st = stg*2 + sti)
  const int bg   = wave & 3;           // batch group 0..3  (b  = bg*2  + bi)
  const int l16  = lane & 15;          // = d (output col)
  const int quad = lane >> 4;
  const int bbase = blockIdx.x * NB;

  // zero X0T (h-pad => defined prefetch at h=39) and XKF (k in [39,64) = 0 for L0)
  {
#pragma unroll
    for (int i = 0; i < 6; i++) { int e = tid + 1024 * i; if (e < NB * 16 * X0TS) X0T[e] = 0.f; }
#pragma unroll
    for (int i = 0; i < 10; i++) { int e = tid + 1024 * i; if (e < NB * 16 * KS) XKF[e] = 0.f; }
  }
  __syncthreads();

  // fill X0T[b][d][h] = x[b][h][d] (xs source) and XKF[b][d][k=h] (L0 xk = x0)
#pragma unroll
  for (int it = 0; it < 5; ++it) {
    int e = tid + it * 1024;           // e = (bb*39 + h)*16 + d, total 4992
    if (e < NB * F0N * 16) {
      float v = x[(size_t)bbase * (F0N * 16) + e];
      int d = e & 15, p = e >> 4;
      int bb = p / F0N, h = p - bb * F0N;
      X0T[(bb * 16 + d) * X0TS + h] = v;
      XKF[(bb * 16 + d) * KS + h] = v;
    }
  }
  __syncthreads();

  const int row0 = (bg * 2 + 0) * 16 + l16;        // (b0, d) row id
  const int row1 = (bg * 2 + 1) * 16 + l16;        // (b1, d) row id
  const float* x0p0 = X0T + row0 * X0TS;
  const float* x0p1 = X0T + row1 * X0TS;

  // loop-invariant per-lane W offset (u16 units): frag (sti,ch) at
  // wloff + sti*1024 + ch*512; per-h base wt + ih*WBLK is wave-uniform (SGPR).
  const int wloff = stg * 2048 + lane * 8;

  // seed dist-1 prefetch: ih = 0 (L0, h0)
  short8 Wc0 = *(const short8*)(wt + wloff);
  short8 Wc1 = *(const short8*)(wt + wloff + 512);
  short8 Wc2 = *(const short8*)(wt + wloff + 1024);
  short8 Wc3 = *(const short8*)(wt + wloff + 1536);

  int ih = 0;                          // flat weight-block index = L*39 + h
#pragma unroll 1
  for (int L = 0; L < 3; ++L) {
    // ---- xk register cache (h-invariant within layer) ----
    const float* xq0 = XKF + row0 * KS + quad * 8;
    const float* xq1 = XKF + row1 * KS + quad * 8;
    floatx4 ka0 = *(const floatx4*)(xq0);        // b0: k = quad*8..+3  (ch0)
    floatx4 ka1 = *(const floatx4*)(xq0 + 4);    //     k = quad*8+4..+7
    floatx4 ka2 = *(const floatx4*)(xq0 + 32);   // ch1: k = 32+quad*8..
    floatx4 ka3 = *(const floatx4*)(xq0 + 36);
    floatx4 kb0 = *(const floatx4*)(xq1);        // b1
    floatx4 kb1 = *(const floatx4*)(xq1 + 4);
    floatx4 kb2 = *(const floatx4*)(xq1 + 32);
    floatx4 kb3 = *(const floatx4*)(xq1 + 36);
    __syncthreads();   // all XKF reads done before any in-place epilogue write

    floatx4 acc0 = {0.f, 0.f, 0.f, 0.f};   // (sti0, b0)
    floatx4 acc1 = {0.f, 0.f, 0.f, 0.f};   // (sti0, b1)
    floatx4 acc2 = {0.f, 0.f, 0.f, 0.f};   // (sti1, b0)
    floatx4 acc3 = {0.f, 0.f, 0.f, 0.f};   // (sti1, b1)

    float xs0 = x0p0[0];
    float xs1 = x0p1[0];

#pragma unroll 1
    for (int h = 0; h < 39; ++h, ++ih) {
      // dist-1 W prefetch: wave-uniform base (SGPR) + invariant lane offset
      int ihn = ih + 1;
      if (ihn > 116) ihn = 116;
      const uint16_t* wbn = wt + (size_t)ihn * WBLK;
      short8 Wn0 = *(const short8*)(wbn + wloff);
      short8 Wn1 = *(const short8*)(wbn + wloff + 512);
      short8 Wn2 = *(const short8*)(wbn + wloff + 1024);
      short8 Wn3 = *(const short8*)(wbn + wloff + 1536);
      // dist-1 xs prefetch (h=38 reads zeroed pad at 39; value unused)
      float xsn0 = x0p0[h + 1];
      float xsn1 = x0p1[h + 1];

      // ---- G = bf16(xs * xk) in regs ----
      floatx4 s0v = {xs0, xs0, xs0, xs0};
      floatx4 s1v = {xs1, xs1, xs1, xs1};
      floatx4 p0 = ka0 * s0v, p1 = ka1 * s0v, p2 = ka2 * s0v, p3 = ka3 * s0v;
      uint32x4 ga0, ga1;
      ga0[0] = cvtpk(p0[0], p0[1]); ga0[1] = cvtpk(p0[2], p0[3]);
      ga0[2] = cvtpk(p1[0], p1[1]); ga0[3] = cvtpk(p1[2], p1[3]);
      ga1[0] = cvtpk(p2[0], p2[1]); ga1[1] = cvtpk(p2[2], p2[3]);
      ga1[2] = cvtpk(p3[0], p3[1]); ga1[3] = cvtpk(p3[2], p3[3]);
      p0 = kb0 * s1v; p1 = kb1 * s1v; p2 = kb2 * s1v; p3 = kb3 * s1v;
      uint32x4 gb0, gb1;
      gb0[0] = cvtpk(p0[0], p0[1]); gb0[1] = cvtpk(p0[2], p0[3]);
      gb0[2] = cvtpk(p1[0], p1[1]); gb0[3] = cvtpk(p1[2], p1[3]);
      gb1[0] = cvtpk(p2[0], p2[1]); gb1[1] = cvtpk(p2[2], p2[3]);
      gb1[2] = cvtpk(p3[0], p3[1]); gb1[3] = cvtpk(p3[2], p3[3]);
      short8 GA0 = __builtin_bit_cast(short8, ga0);
      short8 GA1 = __builtin_bit_cast(short8, ga1);
      short8 GB0 = __builtin_bit_cast(short8, gb0);
      short8 GB1 = __builtin_bit_cast(short8, gb1);

      // ---- 8 MFMAs: 4 persistent acc chains, depth 2 per h ----
      acc0 = __builtin_amdgcn_mfma_f32_16x16x32_bf16(Wc0, GA0, acc0, 0, 0, 0);
      acc1 = __builtin_amdgcn_mfma_f32_16x16x32_bf16(Wc0, GB0, acc1, 0, 0, 0);
      acc2 = __builtin_amdgcn_mfma_f32_16x16x32_bf16(Wc2, GA0, acc2, 0, 0, 0);
      acc3 = __builtin_amdgcn_mfma_f32_16x16x32_bf16(Wc2, GB0, acc3, 0, 0, 0);
      acc0 = __builtin_amdgcn_mfma_f32_16x16x32_bf16(Wc1, GA1, acc0, 0, 0, 0);
      acc1 = __builtin_amdgcn_mfma_f32_16x16x32_bf16(Wc1, GB1, acc1, 0, 0, 0);
      acc2 = __builtin_amdgcn_mfma_f32_16x16x32_bf16(Wc3, GA1, acc2, 0, 0, 0);
      acc3 = __builtin_amdgcn_mfma_f32_16x16x32_bf16(Wc3, GB1, acc3, 0, 0, 0);

      Wc0 = Wn0; Wc1 = Wn1; Wc2 = Wn2; Wc3 = Wn3;
      xs0 = xsn0; xs1 = xsn1;
    }

    // ---- epilogue: bias+relu; in-place xk handoff; sum_d (l16) -> out ----
    const float* bp = (L == 0) ? bias0 : ((L == 1) ? bias1 : bias2);
#define EPI(ACC, STI, BI)                                                     \
    {                                                                         \
      const int b_ = bg * 2 + (BI);                                           \
      const int s0 = (stg * 2 + (STI)) * 16 + quad * 4;                       \
      _Pragma("unroll")                                                       \
      for (int r = 0; r < 4; ++r) {                                           \
        float t = fmaxf((ACC)[r] + bp[s0 + r], 0.f);                          \
        if (L < 2 && stg < 2)                /* xk = relu(z)[:, :64]; k = s */ \
          XKF[(b_ * 16 + l16) * KS + s0 + r] = t;                             \
        float s4 = t;                        /* reduce over d = l16 */        \
        s4 += __shfl_xor(s4, 1);                                              \
        s4 += __shfl_xor(s4, 2);                                              \
        s4 += __shfl_xor(s4, 4);                                              \
        s4 += __shfl_xor(s4, 8);                                              \
        if (l16 == 0) {                                                       \
          int s = s0 + r;                                                     \
          if (L == 2)       out[(size_t)(bbase + b_) * 256 + 128 + s] = s4;   \
          else if (s >= 64) out[(size_t)(bbase + b_) * 256 + L * 64 + (s - 64)] = s4; \
        }                                                                     \
      }                                                                       \
    }
    EPI(acc0, 0, 0)
    EPI(acc1, 0, 1)
    EPI(acc2, 1, 0)
    EPI(acc3, 1, 1)
#undef EPI

    if (L < 2) __syncthreads();   // handoff writes visible before next xk cache load
  }
}

extern "C" void kernel_launch(void* const* d_in, const int* in_sizes, int n_in,
                              void* d_out, int out_size, void* d_ws, size_t ws_size,
                              hipStream_t stream) {
  (void)in_sizes; (void)n_in; (void)out_size; (void)ws_size;
  const float* x  = (const float*)d_in[0];
  const float* w0 = (const float*)d_in[1];
  const float* b0 = (const float*)d_in[2];
  const float* w1 = (const float*)d_in[3];
  const float* b1 = (const float*)d_in[4];
  const float* w2 = (const float*)d_in[5];
  const float* b2 = (const float*)d_in[6];
  uint16_t* wt    = (uint16_t*)d_ws;   // 117 * 8192 * 2 = 1,916,928 B

  cin_prepass<<<NHB2, 256, 0, stream>>>(w0, w1, w2, wt);
  cin_main<<<2048 / NB, 1024, 0, stream>>>(x, b0, b1, b2, wt, (float*)d_out);
}

// Round 6
// 160.714 us; speedup vs baseline: 1.0133x; 1.0133x over previous
//
#include <hip/hip_runtime.h>
#include <stdint.h>
#include <stddef.h>

// ---------------- problem constants ----------------
// B=2048, F0=39, D=16, layers 128/128/128, xk halves to 64 after each layer.
// R17: R15/R16 G-GEMM + codegen fixes. R15/R16 both compiled to VGPR=60 with
// min live set 64+ (ka/kb 32 + acc 16 + Wc 16) and NO scratch -> allocator
// resolved pressure via AGPR shuffling (v_accvgpr_read/write = VALU), ~220
// VALU instr/wave-h vs ~50 in source; MfmaUtil 26%. launch_bounds arg2 is
// only a FLOOR (R16: arg2=2 changed nothing); the occupancy TARGET is pinned
// with amdgpu_waves_per_eu(4,4) -> budget 512/4 = 128 VGPRs, allocator stops
// targeting 8 waves (unreachable anyway: 16-wave block + 62KB LDS). Also:
// inline-asm cvt_pk removed (m240: asm blocks cost ~37% vs plain casts) ->
// __builtin_convertvector f32x8->bf16x8 (4x v_cvt_pk_bf16_f32, RNE, freely
// schedulable), G-build interleaved per chunk to halve transient pressure.
// Grid 256, 1 block/CU (R12/R13: 2 desynced blocks/CU thrash W L1/L2).
#define F0N  39
#define SN   128
#define NB   8             // batches per block
#define X0TS 45            // f32 stride of X0T row (b,d): odd => conflict-free xs reads
#define KS   76            // f32 stride of XKF row (b,d): 16B-aligned rows
#define WBLK 8192          // u16 per (L,h) W block: 8 s-tiles x 2 chunks x 512
#define NHB2 234           // 3*39*2 prepass blocks (one per (L,h,k-half))

typedef __attribute__((ext_vector_type(8))) short short8;     // MFMA A/B operand
typedef __attribute__((ext_vector_type(4))) float floatx4;    // MFMA accumulator
typedef __attribute__((ext_vector_type(8))) float floatx8;
typedef __attribute__((ext_vector_type(8))) __bf16 bf16x8;

__device__ __forceinline__ uint16_t f2bf(float f) {           // RNE f32->bf16
  uint32_t u = __float_as_uint(f);
  u += 0x7fffu + ((u >> 16) & 1u);
  return (uint16_t)(u >> 16);
}

// pack two f32x4 -> one bf16x8 MFMA operand (compiler emits v_cvt_pk_bf16_f32)
__device__ __forceinline__ short8 g8(floatx4 lo, floatx4 hi) {
  floatx8 f = __builtin_shufflevector(lo, hi, 0, 1, 2, 3, 4, 5, 6, 7);
  return __builtin_bit_cast(short8, __builtin_convertvector(f, bf16x8));
}

// ---------------- pre-pass: W fp32 -> bf16 A-fragment blocks ----------------
// One block per (L,h,ch). Output layout identical to R6-R16 (verified):
//   wt[(L*39+h)*WBLK + (st*2+ch)*512 + lane*8 + j],
//   value = W[h][k=ch*32+quad*8+j][s=st*16+l16].
__global__ __launch_bounds__(256) void cin_prepass(
    const float* __restrict__ w0, const float* __restrict__ w1,
    const float* __restrict__ w2, uint16_t* __restrict__ wt) {
  __shared__ float T[32 * 132];               // [k_local][s], +4 pad floats/row
  const int bc = blockIdx.x;                  // 0..233
  const int ch = bc & 1;
  const int lh = bc >> 1;                     // 0..116
  const int L = lh / F0N;
  const int h = lh - L * F0N;
  const float* W = (L == 0) ? w0 : ((L == 1) ? w1 : w2);
  const int fk = (L == 0) ? 39 : 64;
  const int tid = threadIdx.x;

  for (int e = tid; e < 4096; e += 256) {     // coalesced fp32 read
    int kc = e >> 7, s = e & 127;
    int k = ch * 32 + kc;
    T[kc * 132 + s] = (k < fk) ? W[(h * fk + k) * SN + s] : 0.0f;
  }
  __syncthreads();
  uint32_t* dst = (uint32_t*)(wt + (size_t)lh * WBLK);
  for (int i = tid; i < 2048; i += 256) {     // coalesced u32 writes, frag order
    int st = i >> 8, w = i & 255;
    int ln = w >> 2, jp = w & 3;
    int quad = ln >> 4, l16 = ln & 15;
    int k0 = quad * 8 + jp * 2;               // local k within this half
    int s = st * 16 + l16;
    dst[(size_t)(st * 2 + ch) * 256 + w] =
        (uint32_t)f2bf(T[k0 * 132 + s]) | ((uint32_t)f2bf(T[(k0 + 1) * 132 + s]) << 16);
  }
}

// ---------------- fused main kernel ----------------
// 256 blocks x 1024 threads (16 waves), 1 block/CU, 4 waves/SIMD.
// Wave (stg, bg): s-tiles st = stg*2+{0,1}, batches b = bg*2+{0,1}.
// Per layer: xk reg-cache (8 x floatx4); barrier; h-loop (39 iters): dist-1
// W prefetch (4 x dwordx4 from SGPR base + invariant lane offset), dist-1 xs
// prefetch (2 ds_read_b32), per-chunk {G build (pk-muls + cvt_pk), 4 MFMA}
// x2 into 4 persistent accs; epilogue: bias+relu, in-place XKF handoff
// (s<64), shfl-reduce over d=l16, out write.
__global__ __attribute__((amdgpu_waves_per_eu(4, 4))) __launch_bounds__(1024)
void cin_main(
    const float* __restrict__ x,       // (2048, 39, 16) fp32
    const float* __restrict__ bias0, const float* __restrict__ bias1,
    const float* __restrict__ bias2,
    const uint16_t* __restrict__ wt,   // A-frag bf16 weights (d_ws)
    float* __restrict__ out) {         // (2048, 256) fp32

  __shared__ __align__(16) float X0T[NB * 16 * X0TS];  // x0[b][d][h] f32, 23040 B
  __shared__ __align__(16) float XKF[NB * 16 * KS];    // xk[b][d][k] f32,  38912 B

  const int tid  = threadIdx.x;
  const int lane = tid & 63;
  const int wave = tid >> 6;           // 0..15
  const int stg  = wave >> 2;          // s-tile group 0..3 (st = stg*2 + sti)
  const int bg   = wave & 3;           // batch group 0..3  (b  = bg*2  + bi)
  const int l16  = lane & 15;          // = d (output col)
  const int quad = lane >> 4;
  const int bbase = blockIdx.x * NB;

  // zero X0T (h-pad => defined prefetch at h=39) and XKF (k in [39,64) = 0 for L0)
  {
#pragma unroll
    for (int i = 0; i < 6; i++) { int e = tid + 1024 * i; if (e < NB * 16 * X0TS) X0T[e] = 0.f; }
#pragma unroll
    for (int i = 0; i < 10; i++) { int e = tid + 1024 * i; if (e < NB * 16 * KS) XKF[e] = 0.f; }
  }
  __syncthreads();

  // fill X0T[b][d][h] = x[b][h][d] (xs source) and XKF[b][d][k=h] (L0 xk = x0)
#pragma unroll
  for (int it = 0; it < 5; ++it) {
    int e = tid + it * 1024;           // e = (bb*39 + h)*16 + d, total 4992
    if (e < NB * F0N * 16) {
      float v = x[(size_t)bbase * (F0N * 16) + e];
      int d = e & 15, p = e >> 4;
      int bb = p / F0N, h = p - bb * F0N;
      X0T[(bb * 16 + d) * X0TS + h] = v;
      XKF[(bb * 16 + d) * KS + h] = v;
    }
  }
  __syncthreads();

  const int row0 = (bg * 2 + 0) * 16 + l16;        // (b0, d) row id
  const int row1 = (bg * 2 + 1) * 16 + l16;        // (b1, d) row id
  const float* x0p0 = X0T + row0 * X0TS;
  const float* x0p1 = X0T + row1 * X0TS;

  // loop-invariant per-lane W offset (u16 units): frag (sti,ch) at
  // wloff + sti*1024 + ch*512; per-h base wt + ih*WBLK is wave-uniform (SGPR).
  const int wloff = stg * 2048 + lane * 8;

  // seed dist-1 prefetch: ih = 0 (L0, h0)
  short8 Wc0 = *(const short8*)(wt + wloff);
  short8 Wc1 = *(const short8*)(wt + wloff + 512);
  short8 Wc2 = *(const short8*)(wt + wloff + 1024);
  short8 Wc3 = *(const short8*)(wt + wloff + 1536);

  int ih = 0;                          // flat weight-block index = L*39 + h
#pragma unroll 1
  for (int L = 0; L < 3; ++L) {
    // ---- xk register cache (h-invariant within layer) ----
    const float* xq0 = XKF + row0 * KS + quad * 8;
    const float* xq1 = XKF + row1 * KS + quad * 8;
    floatx4 ka0 = *(const floatx4*)(xq0);        // b0: k = quad*8..+3  (ch0)
    floatx4 ka1 = *(const floatx4*)(xq0 + 4);    //     k = quad*8+4..+7
    floatx4 ka2 = *(const floatx4*)(xq0 + 32);   // ch1: k = 32+quad*8..
    floatx4 ka3 = *(const floatx4*)(xq0 + 36);
    floatx4 kb0 = *(const floatx4*)(xq1);        // b1
    floatx4 kb1 = *(const floatx4*)(xq1 + 4);
    floatx4 kb2 = *(const floatx4*)(xq1 + 32);
    floatx4 kb3 = *(const floatx4*)(xq1 + 36);
    __syncthreads();   // all XKF reads done before any in-place epilogue write

    floatx4 acc0 = {0.f, 0.f, 0.f, 0.f};   // (sti0, b0)
    floatx4 acc1 = {0.f, 0.f, 0.f, 0.f};   // (sti0, b1)
    floatx4 acc2 = {0.f, 0.f, 0.f, 0.f};   // (sti1, b0)
    floatx4 acc3 = {0.f, 0.f, 0.f, 0.f};   // (sti1, b1)

    float xs0 = x0p0[0];
    float xs1 = x0p1[0];

#pragma unroll 1
    for (int h = 0; h < 39; ++h, ++ih) {
      // dist-1 W prefetch: wave-uniform base (SGPR) + invariant lane offset
      int ihn = ih + 1;
      if (ihn > 116) ihn = 116;
      const uint16_t* wbn = wt + (size_t)ihn * WBLK;
      short8 Wn0 = *(const short8*)(wbn + wloff);
      short8 Wn1 = *(const short8*)(wbn + wloff + 512);
      short8 Wn2 = *(const short8*)(wbn + wloff + 1024);
      short8 Wn3 = *(const short8*)(wbn + wloff + 1536);
      // dist-1 xs prefetch (h=38 reads zeroed pad at 39; value unused)
      float xsn0 = x0p0[h + 1];
      float xsn1 = x0p1[h + 1];

      floatx4 s0v = {xs0, xs0, xs0, xs0};
      floatx4 s1v = {xs1, xs1, xs1, xs1};

      // ---- chunk 0: G = bf16(xs * xk[k<32]), 4 MFMAs ----
      short8 GA0 = g8(ka0 * s0v, ka1 * s0v);
      short8 GB0 = g8(kb0 * s1v, kb1 * s1v);
      acc0 = __builtin_amdgcn_mfma_f32_16x16x32_bf16(Wc0, GA0, acc0, 0, 0, 0);
      acc1 = __builtin_amdgcn_mfma_f32_16x16x32_bf16(Wc0, GB0, acc1, 0, 0, 0);
      acc2 = __builtin_amdgcn_mfma_f32_16x16x32_bf16(Wc2, GA0, acc2, 0, 0, 0);
      acc3 = __builtin_amdgcn_mfma_f32_16x16x32_bf16(Wc2, GB0, acc3, 0, 0, 0);

      // ---- chunk 1: G = bf16(xs * xk[k>=32]), 4 MFMAs ----
      short8 GA1 = g8(ka2 * s0v, ka3 * s0v);
      short8 GB1 = g8(kb2 * s1v, kb3 * s1v);
      acc0 = __builtin_amdgcn_mfma_f32_16x16x32_bf16(Wc1, GA1, acc0, 0, 0, 0);
      acc1 = __builtin_amdgcn_mfma_f32_16x16x32_bf16(Wc1, GB1, acc1, 0, 0, 0);
      acc2 = __builtin_amdgcn_mfma_f32_16x16x32_bf16(Wc3, GA1, acc2, 0, 0, 0);
      acc3 = __builtin_amdgcn_mfma_f32_16x16x32_bf16(Wc3, GB1, acc3, 0, 0, 0);

      Wc0 = Wn0; Wc1 = Wn1; Wc2 = Wn2; Wc3 = Wn3;
      xs0 = xsn0; xs1 = xsn1;
    }

    // ---- epilogue: bias+relu; in-place xk handoff; sum_d (l16) -> out ----
    const float* bp = (L == 0) ? bias0 : ((L == 1) ? bias1 : bias2);
#define EPI(ACC, STI, BI)                                                     \
    {                                                                         \
      const int b_ = bg * 2 + (BI);                                           \
      const int s0 = (stg * 2 + (STI)) * 16 + quad * 4;                       \
      _Pragma("unroll")                                                       \
      for (int r = 0; r < 4; ++r) {                                           \
        float t = fmaxf((ACC)[r] + bp[s0 + r], 0.f);                          \
        if (L < 2 && stg < 2)                /* xk = relu(z)[:, :64]; k = s */ \
          XKF[(b_ * 16 + l16) * KS + s0 + r] = t;                             \
        float s4 = t;                        /* reduce over d = l16 */        \
        s4 += __shfl_xor(s4, 1);                                              \
        s4 += __shfl_xor(s4, 2);                                              \
        s4 += __shfl_xor(s4, 4);                                              \
        s4 += __shfl_xor(s4, 8);                                              \
        if (l16 == 0) {                                                       \
          int s = s0 + r;                                                     \
          if (L == 2)       out[(size_t)(bbase + b_) * 256 + 128 + s] = s4;   \
          else if (s >= 64) out[(size_t)(bbase + b_) * 256 + L * 64 + (s - 64)] = s4; \
        }                                                                     \
      }                                                                       \
    }
    EPI(acc0, 0, 0)
    EPI(acc1, 0, 1)
    EPI(acc2, 1, 0)
    EPI(acc3, 1, 1)
#undef EPI

    if (L < 2) __syncthreads();   // handoff writes visible before next xk cache load
  }
}

extern "C" void kernel_launch(void* const* d_in, const int* in_sizes, int n_in,
                              void* d_out, int out_size, void* d_ws, size_t ws_size,
                              hipStream_t stream) {
  (void)in_sizes; (void)n_in; (void)out_size; (void)ws_size;
  const float* x  = (const float*)d_in[0];
  const float* w0 = (const float*)d_in[1];
  const float* b0 = (const float*)d_in[2];
  const float* w1 = (const float*)d_in[3];
  const float* b1 = (const float*)d_in[4];
  const float* w2 = (const float*)d_in[5];
  const float* b2 = (const float*)d_in[6];
  uint16_t* wt    = (uint16_t*)d_ws;   // 117 * 8192 * 2 = 1,916,928 B

  cin_prepass<<<NHB2, 256, 0, stream>>>(w0, w1, w2, wt);
  cin_main<<<2048 / NB, 1024, 0, stream>>>(x, b0, b1, b2, wt, (float*)d_out);
}

// Round 7
// 135.004 us; speedup vs baseline: 1.2063x; 1.1904x over previous
//
#include <hip/hip_runtime.h>
#include <stdint.h>
#include <stddef.h>

// ---------------- problem constants ----------------
// B=2048, F0=39, D=16, layers 128/128/128, xk halves to 64 after each layer.
// Factored form: y_h[s,d] = sum_k W[h,k,s]*xk[b,k,d] (MFMA: A=W static, B=xk
// h-invariant -> register-cached per layer); z[b,s,d] = sum_h x0[b,h,d]*y_h[s,d].
// R18: restore the R11 champion (74.2us main; R12-R17 regressions: 2-block/CU
// thrashes the W stream, G-GEMM restructure collapses in regalloc) + the two
// session-validated micro-fixes:
//  (1) X0TS 44->45: odd stride makes the 16 xs ds_read_b32 addresses hit 16
//      distinct banks (validated: SQ_LDS_BANK_CONFLICT 4.69M -> ~0.7M in
//      R12-R17). 4.69M conflict-cyc/dispatch ~= 10% of R11's wall.
//  (2) flat weight-index walk (ih = L*39+h, uniform SALU base; prefetch
//      ihn = min(ih+1,116) rolls into next layer's h0 at h=38) and the h=39
//      dummy iteration is dropped: 2.5% less inner-loop work (neutral-at-
//      worst in R13; its regression was the 2-block/CU config).
// 256 blocks x 1024 threads (16 waves) -> 4 waves/SIMD, ONE block/CU. Wave =
// (st in [0,8), bg in [0,2)): 4 batches x 16 s each; bg-pair waves read
// identical W lines (L1 hit, GPU-wide L2 W traffic halves).
#define F0N  39
#define SN   128
#define NB   8             // batches per block
#define X0TS 45            // f32 stride of X0T row (b,d): 39+6 pad, odd => conflict-free
#define XKTS 72            // u16 stride of XKT row (b,d): 64+8 pad, 16B-aligned
#define WBLK 8192          // u16 per (L,h) W block: 8 s-tiles x 2 chunks x 512
#define NHB2 234           // 3*39*2 prepass blocks (one per (L,h,k-half))

typedef __attribute__((ext_vector_type(8))) short short8;   // MFMA A/B operand
typedef __attribute__((ext_vector_type(4))) float floatx4;  // MFMA accumulator

__device__ __forceinline__ uint16_t f2bf(float f) {         // RNE f32->bf16
  uint32_t u = __float_as_uint(f);
  u += 0x7fffu + ((u >> 16) & 1u);
  return (uint16_t)(u >> 16);
}

// ---------------- pre-pass: W fp32 -> bf16 A-fragment blocks ----------------
// One block per (L,h,ch). Output layout identical to R6-R17 (verified):
//   wt[(L*39+h)*WBLK + (st*2+ch)*512 + lane*8 + j],
//   value = W[h][k=ch*32+quad*8+j][s=st*16+l16].
__global__ __launch_bounds__(256) void cin_prepass(
    const float* __restrict__ w0, const float* __restrict__ w1,
    const float* __restrict__ w2, uint16_t* __restrict__ wt) {
  __shared__ float T[32 * 132];               // [k_local][s], +4 pad floats/row
  const int bc = blockIdx.x;                  // 0..233
  const int ch = bc & 1;
  const int lh = bc >> 1;                     // 0..116
  const int L = lh / F0N;
  const int h = lh - L * F0N;
  const float* W = (L == 0) ? w0 : ((L == 1) ? w1 : w2);
  const int fk = (L == 0) ? 39 : 64;
  const int tid = threadIdx.x;

  for (int e = tid; e < 4096; e += 256) {     // coalesced fp32 read
    int kc = e >> 7, s = e & 127;
    int k = ch * 32 + kc;
    T[kc * 132 + s] = (k < fk) ? W[(h * fk + k) * SN + s] : 0.0f;
  }
  __syncthreads();
  uint32_t* dst = (uint32_t*)(wt + (size_t)lh * WBLK);
  for (int i = tid; i < 2048; i += 256) {     // coalesced u32 writes, frag order
    int st = i >> 8, w = i & 255;
    int ln = w >> 2, jp = w & 3;
    int quad = ln >> 4, l16 = ln & 15;
    int k0 = quad * 8 + jp * 2;               // local k within this half
    int s = st * 16 + l16;
    dst[(size_t)(st * 2 + ch) * 256 + w] =
        (uint32_t)f2bf(T[k0 * 132 + s]) | ((uint32_t)f2bf(T[(k0 + 1) * 132 + s]) << 16);
  }
}

// ---------------- fused main kernel ----------------
// 256 blocks x 1024 threads (16 waves), 1 block/CU, 4 waves/SIMD.
// Block owns NB=8 batches x full s (xk handoff block-local). Wave (st,bg):
// s-tile [st*16,st*16+16) x batches [bg*4, bg*4+4). Per layer: Bf register-
// cached; per h: 2 coalesced global W-frag loads (dist-1 register prefetch,
// no barriers in h-loop, SALU-uniform ih base), 4 scalar x0 ds_reads
// (conflict-free odd stride), 8 MFMA + 16 fmac. Flat weight index ih =
// L*39+h in [0,117); prefetch min(ih+1,116) rolls into next layer's h0 at
// h=38. D-layout: D[s=st*16+quad*4+r][d=l16]; sum_d over l16 bits.
__global__ __launch_bounds__(1024) void cin_main(
    const float* __restrict__ x,       // (2048, 39, 16) fp32
    const float* __restrict__ bias0, const float* __restrict__ bias1,
    const float* __restrict__ bias2,
    const uint16_t* __restrict__ wt,   // A-frag bf16 weights (d_ws)
    float* __restrict__ out) {         // (2048, 256) fp32

  __shared__ __align__(16) float    X0T[NB * 16 * X0TS];  // x0[b][d][h] f32, 23040 B
  __shared__ __align__(16) uint16_t XKT[NB * 16 * XKTS];  // xk[b][d][k] bf16, 18432 B

  const int tid  = threadIdx.x;
  const int lane = tid & 63;
  const int wave = tid >> 6;           // 0..15
  const int st   = wave >> 1;          // s-tile 0..7
  const int bg   = wave & 1;           // batch group 0..1
  const int l16  = lane & 15;          // = d (output col)
  const int quad = lane >> 4;
  const int bbase = blockIdx.x * NB;

  // zero X0T (h-pad 39..44 must be 0) and XKT (k-pad for L0)
  {
    float* p = X0T;                    // 5760 floats
#pragma unroll
    for (int i = 0; i < 6; i++) { int e = tid + 1024 * i; if (e < NB * 16 * X0TS) p[e] = 0.f; }
    uint32_t* q = (uint32_t*)XKT;      // 4608 dwords
#pragma unroll
    for (int i = 0; i < 5; i++) { int e = tid + 1024 * i; if (e < NB * 16 * XKTS / 2) q[e] = 0u; }
  }
  __syncthreads();

  // fill X0T[b][d][h] = x[bbase+b][h][d]  (coalesced read, LDS transpose-scatter)
#pragma unroll
  for (int it = 0; it < 5; ++it) {
    int e = tid + it * 1024;           // e = (b*39 + h)*16 + d, total 4992
    if (e < NB * F0N * 16) {
      float v = x[(size_t)bbase * (F0N * 16) + e];
      int d = e & 15, p = e >> 4;
      int b = p / F0N, h = p - b * F0N;
      X0T[(b * 16 + d) * X0TS + h] = v;
    }
  }
  __syncthreads();

  // build layer-0 XKT[b][d][k] = bf16(x0[b][k][d]) for k<39, 0 for k in [39,64)
  if (tid < 512) {
    int b = tid >> 6, d = (tid >> 2) & 15, kg = tid & 3;
    const float* src = &X0T[(b * 16 + d) * X0TS];
    uint32_t* drow = (uint32_t*)&XKT[(b * 16 + d) * XKTS + kg * 16];
#pragma unroll
    for (int i2 = 0; i2 < 8; i2++) {
      int k0 = kg * 16 + i2 * 2;
      uint32_t lo = (k0 < 39)     ? (uint32_t)f2bf(src[k0])     : 0u;
      uint32_t hi = (k0 + 1 < 39) ? (uint32_t)f2bf(src[k0 + 1]) : 0u;
      drow[i2] = lo | (hi << 16);
    }
  }
  __syncthreads();   // XKT build visible for Bf loads

  // per-lane constant W offset (u16 units) — bg-pair waves share lines (L1)
  const int stlane = st * 1024 + lane * 8;

  // seed dist-1 prefetch: ih = 0 (L0, h0)
  short8 Wc0 = *(const short8*)(wt + stlane);
  short8 Wc1 = *(const short8*)(wt + stlane + 512);

  int ih = 0;                          // flat weight-block index = L*39 + h
#pragma unroll 1
  for (int L = 0; L < 3; ++L) {
    // register-cache B-fragments (h-invariant within layer); b = bg*4 + bi
    short8 Bf0[4], Bf1[4];
#pragma unroll
    for (int bi = 0; bi < 4; ++bi) {
      const uint16_t* r = XKT + ((bg * 4 + bi) * 16 + l16) * XKTS + quad * 8;
      Bf0[bi] = *(const short8*)r;          // k 0..31 chunk
      Bf1[bi] = *(const short8*)(r + 32);   // k 32..63 chunk
    }
    const float* bp = (L == 0) ? bias0 : ((L == 1) ? bias1 : bias2);
    float bvr[4];
#pragma unroll
    for (int r = 0; r < 4; ++r) bvr[r] = bp[st * 16 + quad * 4 + r];

    floatx4 z[4] = {};
    const floatx4 zero4 = {0.f, 0.f, 0.f, 0.f};

#pragma unroll 1
    for (int h = 0; h < 39; ++h, ++ih) {
      // dist-1 prefetch; uniform SALU base (ih+1 at h=38 IS next layer's h0)
      int ihn = ih + 1;
      if (ihn > 116) ihn = 116;
      const uint16_t* wb = wt + (size_t)ihn * WBLK + stlane;
      short8 Wn0 = *(const short8*)(wb);
      short8 Wn1 = *(const short8*)(wb + 512);

      // x0 scalars; broadcast ds_read_b32, conflict-free (odd stride)
      float xs[4];
#pragma unroll
      for (int bi = 0; bi < 4; ++bi)
        xs[bi] = X0T[((bg * 4 + bi) * 16 + l16) * X0TS + h];

#pragma unroll
      for (int bi = 0; bi < 4; ++bi) {
        floatx4 y = __builtin_amdgcn_mfma_f32_16x16x32_bf16(Wc0, Bf0[bi], zero4, 0, 0, 0);
        y = __builtin_amdgcn_mfma_f32_16x16x32_bf16(Wc1, Bf1[bi], y, 0, 0, 0);
#pragma unroll
        for (int r = 0; r < 4; ++r) z[bi][r] += xs[bi] * y[r];
      }
      Wc0 = Wn0;
      Wc1 = Wn1;
    }

    // ---- epilogue: bias+relu; xk handoff; sum_d (over l16) -> out ----
#pragma unroll
    for (int bi = 0; bi < 4; ++bi) {
      const int b = bg * 4 + bi;
#pragma unroll
      for (int r = 0; r < 4; ++r) {
        float t = fmaxf(z[bi][r] + bvr[r], 0.f);
        if (L < 2 && st < 4)               // xk = relu(z)[:, :64]; k = s < 64
          XKT[(b * 16 + l16) * XKTS + st * 16 + quad * 4 + r] = f2bf(t);
        float s4 = t;                       // reduce over d = l16 (bits 0..3)
        s4 += __shfl_xor(s4, 1);
        s4 += __shfl_xor(s4, 2);
        s4 += __shfl_xor(s4, 4);
        s4 += __shfl_xor(s4, 8);
        if (l16 == 0) {
          int s = st * 16 + quad * 4 + r;
          // concat: L0 s64:128 -> 0:64 ; L1 s64:128 -> 64:128 ; L2 s -> 128:256
          if (L == 2)       out[(size_t)(bbase + b) * 256 + 128 + s] = s4;
          else if (s >= 64) out[(size_t)(bbase + b) * 256 + L * 64 + (s - 64)] = s4;
        }
      }
    }
    if (L < 2) __syncthreads();   // handoff writes visible before next-layer Bf loads
  }
}

extern "C" void kernel_launch(void* const* d_in, const int* in_sizes, int n_in,
                              void* d_out, int out_size, void* d_ws, size_t ws_size,
                              hipStream_t stream) {
  (void)in_sizes; (void)n_in; (void)out_size; (void)ws_size;
  const float* x  = (const float*)d_in[0];
  const float* w0 = (const float*)d_in[1];
  const float* b0 = (const float*)d_in[2];
  const float* w1 = (const float*)d_in[3];
  const float* b1 = (const float*)d_in[4];
  const float* w2 = (const float*)d_in[5];
  const float* b2 = (const float*)d_in[6];
  uint16_t* wt    = (uint16_t*)d_ws;   // 117 * 8192 * 2 = 1,916,928 B

  cin_prepass<<<NHB2, 256, 0, stream>>>(w0, w1, w2, wt);
  cin_main<<<256, 1024, 0, stream>>>(x, b0, b1, b2, wt, (float*)d_out);
}